// Round 9
// baseline (563.279 us; speedup 1.0000x reference)
//
#include <hip/hip_runtime.h>
#include <hip/hip_bf16.h>
#include <cmath>

#define NLV 16
#define TBL_SIZE (1u << 19)

// tier2 block-local sort (fallback)
#define SORT_PPB 8192
#define SORT_THREADS 512
#define SORT_NKEYS 4096

// tier1 global sort: 32^3 Morton buckets, global-atomic hist + scatter
#define KB15 32768
#define SCAN_THREADS 1024

struct LevelConsts {
    float scale[NLV];
    int   res[NLV];
    int   dense[NLV];
};

// ---------- bf16 helpers ----------
__device__ __forceinline__ unsigned int f32_to_bf16_rne(float f) {
    unsigned int u = __float_as_uint(f);
    return (u + 0x7FFFu + ((u >> 16) & 1u)) >> 16;
}
__device__ __forceinline__ unsigned int pack_bf16(float a, float b) {
    return f32_to_bf16_rne(a) | (f32_to_bf16_rne(b) << 16);
}
__device__ __forceinline__ short f32_to_bf16_s(float f) {
    return (short)f32_to_bf16_rne(f);
}
__device__ __forceinline__ float bf16lo_to_f32(unsigned int g) {
    return __uint_as_float(g << 16);
}
__device__ __forceinline__ float bf16hi_to_f32(unsigned int g) {
    return __uint_as_float(g & 0xFFFF0000u);
}

typedef __attribute__((ext_vector_type(8))) short bf16x8;
typedef __attribute__((ext_vector_type(4))) float f32x4;
typedef __attribute__((ext_vector_type(2))) unsigned int u32x2;
typedef __attribute__((ext_vector_type(4))) unsigned int u32x4;

// ---------- Morton keys ----------
__device__ __forceinline__ unsigned spread3(unsigned x) {
    x &= 0x3FFu;
    x = (x | (x << 16)) & 0x030000FFu;
    x = (x | (x << 8))  & 0x0300F00Fu;
    x = (x | (x << 4))  & 0x030C30C3u;
    x = (x | (x << 2))  & 0x09249249u;
    return x;
}
__device__ __forceinline__ unsigned key12(float px, float py, float pz) {
    float x = fminf(fmaxf((px + 1.0f) * 0.5f, 0.0f), 1.0f);
    float y = fminf(fmaxf((py + 1.0f) * 0.5f, 0.0f), 1.0f);
    float z = fminf(fmaxf((pz + 1.0f) * 0.5f, 0.0f), 1.0f);
    int ix = min((int)(x * 16.0f), 15);
    int iy = min((int)(y * 16.0f), 15);
    int iz = min((int)(z * 16.0f), 15);
    return spread3((unsigned)ix) | (spread3((unsigned)iy) << 1) | (spread3((unsigned)iz) << 2);
}
__device__ __forceinline__ unsigned key15(float px, float py, float pz) {
    float x = fminf(fmaxf((px + 1.0f) * 0.5f, 0.0f), 1.0f);
    float y = fminf(fmaxf((py + 1.0f) * 0.5f, 0.0f), 1.0f);
    float z = fminf(fmaxf((pz + 1.0f) * 0.5f, 0.0f), 1.0f);
    int ix = min((int)(x * 32.0f), 31);
    int iy = min((int)(y * 32.0f), 31);
    int iz = min((int)(z * 32.0f), 31);
    return spread3((unsigned)ix) | (spread3((unsigned)iy) << 1) | (spread3((unsigned)iz) << 2);
}

// ---------- tier1 K1: cvt || global-atomic hist ----------
// hist[] pre-zeroed by hipMemsetAsync (stream-ordered). 32K counters are
// L2-resident; ~30 collisions/bucket over the whole kernel -> no contention.
__global__ __launch_bounds__(256) void cvt_and_hist_at(
    const float* __restrict__ tablef32, unsigned int* __restrict__ tbl_out, int npairs,
    const float* __restrict__ pts, unsigned int* __restrict__ hist, int N, int histBlocks)
{
    if ((int)blockIdx.x < histBlocks) {
        int i = blockIdx.x * 256 + threadIdx.x;
        int stride = histBlocks * 256;
        for (; i < N; i += stride) {
            unsigned k = key15(pts[3 * i + 0], pts[3 * i + 1], pts[3 * i + 2]);
            atomicAdd(&hist[k], 1u);
        }
    } else {
        int b = blockIdx.x - histBlocks;
        int n2 = npairs >> 1;
        int i = b * 256 + threadIdx.x;
        int stride = ((int)gridDim.x - histBlocks) * 256;
        const f32x4* in4 = (const f32x4*)tablef32;
        u32x2* out2 = (u32x2*)tbl_out;
        for (; i < n2; i += stride) {
            f32x4 v = __builtin_nontemporal_load(&in4[i]);
            u32x2 o;
            o.x = pack_bf16(v.x, v.y);
            o.y = pack_bf16(v.z, v.w);
            __builtin_nontemporal_store(o, &out2[i]);
        }
    }
}

// ---------- tier1 K2: in-place exclusive scan of hist[KB15] (one block) ----------
__global__ __launch_bounds__(SCAN_THREADS) void scan_tot(unsigned int* __restrict__ tot) {
    __shared__ unsigned wsum[SCAN_THREADS / 64];
    const int t = threadIdx.x, lane = t & 63, wid = t >> 6;
    unsigned loc[KB15 / SCAN_THREADS];
    unsigned s = 0;
#pragma unroll
    for (int j = 0; j < KB15 / SCAN_THREADS; j++) { loc[j] = tot[t * (KB15 / SCAN_THREADS) + j]; s += loc[j]; }
    unsigned x = s;
#pragma unroll
    for (int d = 1; d < 64; d <<= 1) {
        unsigned y = __shfl_up(x, d, 64);
        if (lane >= d) x += y;
    }
    unsigned wex = x - s;
    if (lane == 63) wsum[wid] = x;
    __syncthreads();
    if (t == 0) {
        unsigned r = 0;
        for (int i = 0; i < SCAN_THREADS / 64; i++) { unsigned tt = wsum[i]; wsum[i] = r; r += tt; }
    }
    __syncthreads();
    unsigned run = wex + wsum[wid];
#pragma unroll
    for (int j = 0; j < KB15 / SCAN_THREADS; j++) { tot[t * (KB15 / SCAN_THREADS) + j] = run; run += loc[j]; }
}

// ---------- tier1 K3: atomic scatter (cur consumed as cursors) ----------
// Intra-bucket order is nondeterministic; results are per-point and scattered
// back by original index, so final output is order-independent (bit-identical).
__global__ __launch_bounds__(256) void scatter_at(
    const float* __restrict__ pts, unsigned int* __restrict__ cur,
    f32x4* __restrict__ spts4, int N)
{
    int i = blockIdx.x * 256 + threadIdx.x;
    int stride = gridDim.x * 256;
    for (; i < N; i += stride) {
        float px = pts[3 * i + 0];
        float py = pts[3 * i + 1];
        float pz = pts[3 * i + 2];
        unsigned k = key15(px, py, pz);
        unsigned pos = atomicAdd(&cur[k], 1u);
        f32x4 o;
        o.x = px; o.y = py; o.z = pz; o.w = __uint_as_float((unsigned)i);
        spts4[pos] = o;
    }
}

// ---------- tier2: fused cvt || block-local sort (proven R5 path) ------
__global__ __launch_bounds__(SORT_THREADS) void cvt_and_sort(
    const float* __restrict__ tablef32, unsigned int* __restrict__ tbl_out, int npairs,
    const float* __restrict__ pts, f32x4* __restrict__ spts4, int N, int sortBlocks)
{
    __shared__ unsigned hist[SORT_NKEYS];
    __shared__ unsigned wsum[SORT_THREADS / 64];

    if ((int)blockIdx.x < sortBlocks) {
        const int sb   = blockIdx.x;
        const int base = sb * SORT_PPB;
        const int cnt  = min(SORT_PPB, N - base);
        const int tid  = threadIdx.x;
        const int lane = tid & 63, wid = tid >> 6;

        for (int i = tid; i < SORT_NKEYS; i += SORT_THREADS) hist[i] = 0u;
        __syncthreads();

        unsigned short keys[16];
#pragma unroll
        for (int q = 0; q < 16; q++) {
            int idx = q * SORT_THREADS + tid;
            unsigned k = 0xFFFFu;
            if (idx < cnt) {
                int p = base + idx;
                k = key12(pts[3 * p + 0], pts[3 * p + 1], pts[3 * p + 2]);
                atomicAdd(&hist[k], 1u);
            }
            keys[q] = (unsigned short)k;
        }
        __syncthreads();

        unsigned loc[8], s = 0;
#pragma unroll
        for (int j = 0; j < 8; j++) { loc[j] = hist[tid * 8 + j]; s += loc[j]; }
        unsigned x = s;
#pragma unroll
        for (int d = 1; d < 64; d <<= 1) {
            unsigned y = __shfl_up(x, d, 64);
            if (lane >= d) x += y;
        }
        unsigned wex = x - s;
        if (lane == 63) wsum[wid] = x;
        __syncthreads();
        if (tid == 0) {
            unsigned r = 0;
            for (int i = 0; i < SORT_THREADS / 64; i++) { unsigned t2 = wsum[i]; wsum[i] = r; r += t2; }
        }
        __syncthreads();
        unsigned run = wex + wsum[wid];
#pragma unroll
        for (int j = 0; j < 8; j++) { hist[tid * 8 + j] = run; run += loc[j]; }
        __syncthreads();

#pragma unroll
        for (int q = 0; q < 16; q++) {
            int idx = q * SORT_THREADS + tid;
            if (idx < cnt) {
                int p = base + idx;
                float px = pts[3 * p + 0];
                float py = pts[3 * p + 1];
                float pz = pts[3 * p + 2];
                unsigned pos = atomicAdd(&hist[keys[q]], 1u);
                f32x4 o;
                o.x = px; o.y = py; o.z = pz; o.w = __uint_as_float((unsigned)p);
                spts4[base + pos] = o;
            }
        }
    } else {
        int b = blockIdx.x - sortBlocks;
        int n2 = npairs >> 1;
        int i = b * SORT_THREADS + threadIdx.x;
        int stride = ((int)gridDim.x - sortBlocks) * SORT_THREADS;
        const f32x4* in4 = (const f32x4*)tablef32;
        u32x2* out2 = (u32x2*)tbl_out;
        for (; i < n2; i += stride) {
            f32x4 v = __builtin_nontemporal_load(&in4[i]);
            u32x2 o;
            o.x = pack_bf16(v.x, v.y);
            o.y = pack_bf16(v.z, v.w);
            __builtin_nontemporal_store(o, &out2[i]);
        }
    }
}

// standalone cvt for tier3
__global__ __launch_bounds__(256) void cvt_table(const float* __restrict__ in,
                                                 unsigned int* __restrict__ out, int npairs) {
    int n2 = npairs >> 1;
    int i = blockIdx.x * 256 + threadIdx.x;
    int stride = gridDim.x * 256;
    const f32x4* in4 = (const f32x4*)in;
    u32x2* out2 = (u32x2*)out;
    for (; i < n2; i += stride) {
        f32x4 v = __builtin_nontemporal_load(&in4[i]);
        u32x2 o;
        o.x = pack_bf16(v.x, v.y);
        o.y = pack_bf16(v.z, v.w);
        __builtin_nontemporal_store(o, &out2[i]);
    }
}

// ---------- kernel B: level-major hash-grid encode ----------
// 2D grid, blockIdx.y = level. DO NOT flatten: x-major dispatch order keeps
// only 1-2 levels' tables (2-4MB) hot in L2 at any instant — this temporal
// level-locality is the load-bearing optimization (R4 flattening: 265->455us).
#define ENC_P 4
template<int PSTRIDE>
__global__ __launch_bounds__(256) void encode_lvl(
    const float* __restrict__ points,
    const unsigned int* __restrict__ tbl,
    unsigned int* __restrict__ enc,
    int N, LevelConsts C)
{
    const int level = blockIdx.y;
    const float sc    = C.scale[level];
    const int   res   = C.res[level];
    const int   dense = C.dense[level];
    const unsigned int* __restrict__ t = tbl + (size_t)level * TBL_SIZE;
    unsigned int* __restrict__ eo = enc + (size_t)level * N;

    const int base = blockIdx.x * (256 * ENC_P) + threadIdx.x;

    int   pt[ENC_P];
    int   valid[ENC_P];
    float wx[ENC_P], wy[ENC_P], wz[ENC_P];
    unsigned int i0a[ENC_P][4], i1a[ENC_P][4];

#pragma unroll
    for (int q = 0; q < ENC_P; q++) {
        pt[q] = base + q * 256;
        valid[q] = pt[q] < N;
        int p = valid[q] ? pt[q] : 0;
        float px, py, pz;
        if (PSTRIDE == 4) {
            f32x4 v = *(const f32x4*)&points[(size_t)p * 4];
            px = v.x; py = v.y; pz = v.z;
        } else {
            px = points[p * 3 + 0];
            py = points[p * 3 + 1];
            pz = points[p * 3 + 2];
        }
        float x = fminf(fmaxf((px + 1.0f) * 0.5f, 0.0f), 1.0f);
        float y = fminf(fmaxf((py + 1.0f) * 0.5f, 0.0f), 1.0f);
        float z = fminf(fmaxf((pz + 1.0f) * 0.5f, 0.0f), 1.0f);

        float fx = x * sc + 0.5f;
        float fy = y * sc + 0.5f;
        float fz = z * sc + 0.5f;
        float f0x = floorf(fx), f0y = floorf(fy), f0z = floorf(fz);
        wx[q] = fx - f0x; wy[q] = fy - f0y; wz[q] = fz - f0z;
        int ix0 = min(max((int)f0x, 0), res - 1);
        int iy0 = min(max((int)f0y, 0), res - 1);
        int iz0 = min(max((int)f0z, 0), res - 1);
        int ix1 = min(ix0 + 1, res - 1);
        int iy1 = min(iy0 + 1, res - 1);
        int iz1 = min(iz0 + 1, res - 1);

#pragma unroll
        for (int m = 0; m < 4; m++) {
            unsigned int uy = (unsigned int)((m & 1) ? iy1 : iy0);
            unsigned int uz = (unsigned int)((m & 2) ? iz1 : iz0);
            unsigned int i0, i1;
            if (dense) {
                unsigned int b = (unsigned int)res * uy + (unsigned int)(res * res) * uz;
                i0 = (unsigned int)ix0 + b;
                i1 = (unsigned int)ix1 + b;
            } else {
                unsigned int H = uy * 2654435761u ^ uz * 805459861u;
                i0 = ((unsigned int)ix0 ^ H) & (TBL_SIZE - 1u);
                i1 = ((unsigned int)ix1 ^ H) & (TBL_SIZE - 1u);
            }
            i0a[q][m] = i0;
            i1a[q][m] = i1;
        }
    }

    u32x2 pr[ENC_P][4];
#pragma unroll
    for (int q = 0; q < ENC_P; q++)
#pragma unroll
        for (int m = 0; m < 4; m++)
            pr[q][m] = *(const u32x2*)(t + (i0a[q][m] & ~1u));

    unsigned int ex[ENC_P][4];
#pragma unroll
    for (int q = 0; q < ENC_P; q++)
#pragma unroll
        for (int m = 0; m < 4; m++) {
            unsigned int i0 = i0a[q][m], i1 = i1a[q][m];
            unsigned int e = 0u;
            if (i1 != (i0 ^ 1u)) e = t[i1];
            ex[q][m] = e;
        }

#pragma unroll
    for (int q = 0; q < ENC_P; q++) {
        float e0 = 0.0f, e1 = 0.0f;
        float wxq = wx[q];
#pragma unroll
        for (int m = 0; m < 4; m++) {
            unsigned int i0 = i0a[q][m], i1 = i1a[q][m];
            u32x2 P = pr[q][m];
            unsigned int v0   = (i0 & 1u) ? P.y : P.x;
            unsigned int vpar = (i0 & 1u) ? P.x : P.y;
            unsigned int v1   = (i1 == (i0 ^ 1u)) ? vpar : ex[q][m];
            float wyz = (((m & 1) ? wy[q] : 1.0f - wy[q])) *
                        (((m & 2) ? wz[q] : 1.0f - wz[q]));
            float w0 = wyz * (1.0f - wxq);
            float w1 = wyz * wxq;
            e0 = fmaf(w0, bf16lo_to_f32(v0), e0);
            e0 = fmaf(w1, bf16lo_to_f32(v1), e0);
            e1 = fmaf(w0, bf16hi_to_f32(v0), e1);
            e1 = fmaf(w1, bf16hi_to_f32(v1), e1);
        }
        if (valid[q]) __builtin_nontemporal_store(pack_bf16(e0, e1), &eo[pt[q]]);
    }
}

// ---------- kernel C: persistent fused dual-MLP via MFMA ----------
__global__ __launch_bounds__(256, 4) void mlp_kernel(
    const unsigned int* __restrict__ enc,
    const float* __restrict__ dw1, const float* __restrict__ dw2,
    const float* __restrict__ fw1, const float* __restrict__ fw2,
    const unsigned int* __restrict__ perm,   // spts4.w (stride 4), or null
    float* __restrict__ out, int N, int ntiles)
{
    __shared__ unsigned int hsh[4][16][68];
    __shared__ float sOut[4][256];

    const int tid  = threadIdx.x;
    const int wave = tid >> 6;
    const int lane = tid & 63;
    const int l15 = lane & 15;
    const int quad = lane >> 4;

    bf16x8 B1[8];
#pragma unroll
    for (int nt = 0; nt < 8; nt++) {
        int col = nt * 16 + l15;
        const float* w = (col < 64) ? (dw1 + col) : (fw1 + (col - 64));
#pragma unroll
        for (int j = 0; j < 8; j++) {
            int k = quad * 8 + j;
            B1[nt][j] = f32_to_bf16_s(w[k * 64]);
        }
    }

    bf16x8 B2[4];
#pragma unroll
    for (int s = 0; s < 4; s++) {
#pragma unroll
        for (int j = 0; j < 8; j++) {
            int k_lds = s * 32 + quad * 8 + j;
            int hu = ((k_lds & 7) << 4) | (k_lds >> 3);
            float v = 0.0f;
            if (l15 == 0)      v = (hu < 64)  ? dw2[hu] : 0.0f;
            else if (l15 < 4)  v = (hu >= 64) ? fw2[(hu - 64) * 3 + (l15 - 1)] : 0.0f;
            B2[s][j] = f32_to_bf16_s(v);
        }
    }

    for (int tile = blockIdx.x; tile < ntiles; tile += gridDim.x) {
        const int wbase = tile * 256 + wave * 64;

        unsigned int au[4][4];
#pragma unroll
        for (int sub = 0; sub < 4; sub++) {
            int ptc = min(wbase + sub * 16 + l15, N - 1);
#pragma unroll
            for (int j = 0; j < 4; j++)
                au[sub][j] = enc[(size_t)(quad * 4 + j) * N + ptc];
        }

#pragma unroll
        for (int sub = 0; sub < 4; sub++) {
            union { unsigned int u[4]; bf16x8 v; } acvt;
#pragma unroll
            for (int j = 0; j < 4; j++) acvt.u[j] = au[sub][j];

            f32x4 acc1[8];
#pragma unroll
            for (int nt = 0; nt < 8; nt++) {
                acc1[nt] = (f32x4){0.0f, 0.0f, 0.0f, 0.0f};
                acc1[nt] = __builtin_amdgcn_mfma_f32_16x16x32_bf16(acvt.v, B1[nt], acc1[nt], 0, 0, 0);
            }

#pragma unroll
            for (int r = 0; r < 4; r++) {
                u32x4 pk;
#pragma unroll
                for (int d = 0; d < 4; d++) {
                    float h0 = fmaxf(acc1[2 * d + 0][r], 0.0f);
                    float h1 = fmaxf(acc1[2 * d + 1][r], 0.0f);
                    pk[d] = pack_bf16(h0, h1);
                }
                *(u32x4*)&hsh[wave][quad * 4 + r][l15 * 4] = pk;
            }

            f32x4 p0 = (f32x4){0,0,0,0}, p1 = (f32x4){0,0,0,0};
            f32x4 p2 = (f32x4){0,0,0,0}, p3 = (f32x4){0,0,0,0};
            {
                bf16x8 a0 = *(const bf16x8*)&hsh[wave][l15][0 * 16 + quad * 4];
                bf16x8 a1 = *(const bf16x8*)&hsh[wave][l15][1 * 16 + quad * 4];
                bf16x8 a2 = *(const bf16x8*)&hsh[wave][l15][2 * 16 + quad * 4];
                bf16x8 a3 = *(const bf16x8*)&hsh[wave][l15][3 * 16 + quad * 4];
                p0 = __builtin_amdgcn_mfma_f32_16x16x32_bf16(a0, B2[0], p0, 0, 0, 0);
                p1 = __builtin_amdgcn_mfma_f32_16x16x32_bf16(a1, B2[1], p1, 0, 0, 0);
                p2 = __builtin_amdgcn_mfma_f32_16x16x32_bf16(a2, B2[2], p2, 0, 0, 0);
                p3 = __builtin_amdgcn_mfma_f32_16x16x32_bf16(a3, B2[3], p3, 0, 0, 0);
            }
            f32x4 acc2;
#pragma unroll
            for (int r = 0; r < 4; r++) acc2[r] = (p0[r] + p1[r]) + (p2[r] + p3[r]);

            if (l15 < 4) {
#pragma unroll
                for (int r = 0; r < 4; r++)
                    sOut[wave][(sub * 16 + quad * 4 + r) * 4 + l15] = acc2[r];
            }
        }

        if (perm) {
            int p = wbase + lane;
            if (p < N) {
                unsigned int o = perm[(size_t)p * 4 + 3];
                f32x4 v = *(const f32x4*)&sOut[wave][lane * 4];
                float d = v[0];
                d = (d > 20.0f) ? d : log1pf(expf(d));
                out[(size_t)3 * N + o] = d;
                float r0 = 1.0f / (1.0f + expf(-v[1]));
                float g0 = 1.0f / (1.0f + expf(-v[2]));
                float b0 = 1.0f / (1.0f + expf(-v[3]));
                out[(size_t)o * 3 + 0] = r0;
                out[(size_t)o * 3 + 1] = g0;
                out[(size_t)o * 3 + 2] = b0;
            }
        } else {
            long long cmax = ((long long)N - wbase) * 3;
#pragma unroll
            for (int round = 0; round < 3; round++) {
                int f = round * 64 + lane;
                int lp = f / 3, c = f - lp * 3;
                float v = sOut[wave][lp * 4 + 1 + c];
                v = 1.0f / (1.0f + expf(-v));
                if (f < cmax) out[(size_t)wbase * 3 + f] = v;
            }
            {
                int p = wbase + lane;
                float v = sOut[wave][lane * 4];
                v = (v > 20.0f) ? v : log1pf(expf(v));
                if (p < N) out[(size_t)3 * N + p] = v;
            }
        }
    }
}

// ---------- fallback: round-1 fused kernel (tiny ws) ----------
__global__ __launch_bounds__(256) void nerf_fused(
    const float* __restrict__ points,
    const float* __restrict__ table,
    const float* __restrict__ dw1, const float* __restrict__ dw2,
    const float* __restrict__ fw1, const float* __restrict__ fw2,
    float* __restrict__ out, int N, LevelConsts C)
{
    __shared__ float sD[64 * 32];
    __shared__ float sF[64 * 32];
    __shared__ float sDw2[64];
    __shared__ float sFw2[64 * 3];

    for (int idx = threadIdx.x; idx < 2048; idx += 256) {
        int i = idx >> 6;
        int j = idx & 63;
        sD[j * 32 + i] = dw1[idx];
        sF[j * 32 + i] = fw1[idx];
    }
    if (threadIdx.x < 64)  sDw2[threadIdx.x] = dw2[threadIdx.x];
    if (threadIdx.x < 192) sFw2[threadIdx.x] = fw2[threadIdx.x];
    __syncthreads();

    int gid = blockIdx.x * 256 + threadIdx.x;
    if (gid >= N) return;

    float px = points[gid * 3 + 0];
    float py = points[gid * 3 + 1];
    float pz = points[gid * 3 + 2];
    float x = fminf(fmaxf((px + 1.0f) * 0.5f, 0.0f), 1.0f);
    float y = fminf(fmaxf((py + 1.0f) * 0.5f, 0.0f), 1.0f);
    float z = fminf(fmaxf((pz + 1.0f) * 0.5f, 0.0f), 1.0f);

    float enc[32];

#pragma unroll
    for (int l = 0; l < NLV; l++) {
        const float sc = C.scale[l];
        const int   res = C.res[l];
        const int   dense = C.dense[l];
        const float* __restrict__ tbl = table + (size_t)l * TBL_SIZE * 2;

        float fx = x * sc + 0.5f;
        float fy = y * sc + 0.5f;
        float fz = z * sc + 0.5f;
        float f0x = floorf(fx), f0y = floorf(fy), f0z = floorf(fz);
        float wx = fx - f0x, wy = fy - f0y, wz = fz - f0z;
        int ix0 = min(max((int)f0x, 0), res - 1);
        int iy0 = min(max((int)f0y, 0), res - 1);
        int iz0 = min(max((int)f0z, 0), res - 1);
        int ix1 = min(ix0 + 1, res - 1);
        int iy1 = min(iy0 + 1, res - 1);
        int iz1 = min(iz0 + 1, res - 1);

        float e0 = 0.0f, e1 = 0.0f;
#pragma unroll
        for (int c = 0; c < 8; c++) {
            int cx = (c & 4) ? ix1 : ix0;
            int cy = (c & 2) ? iy1 : iy0;
            int cz = (c & 1) ? iz1 : iz0;
            float wgt = (((c & 4) ? wx : 1.0f - wx) *
                         ((c & 2) ? wy : 1.0f - wy)) *
                         ((c & 1) ? wz : 1.0f - wz);
            unsigned int idx;
            if (dense) {
                idx = (unsigned int)(cx + res * cy + res * res * cz);
            } else {
                idx = ((unsigned int)cx * 1u
                     ^ (unsigned int)cy * 2654435761u
                     ^ (unsigned int)cz * 805459861u) & (TBL_SIZE - 1u);
            }
            const float2 g = *(const float2*)(tbl + (size_t)idx * 2);
            e0 = fmaf(wgt, g.x, e0);
            e1 = fmaf(wgt, g.y, e1);
        }
        enc[2 * l + 0] = e0;
        enc[2 * l + 1] = e1;
    }

    float dacc = 0.0f, c0 = 0.0f, c1 = 0.0f, c2 = 0.0f;
    for (int j = 0; j < 64; j++) {
        float hd = 0.0f, hf = 0.0f;
        const float* __restrict__ colD = &sD[j * 32];
        const float* __restrict__ colF = &sF[j * 32];
#pragma unroll
        for (int i = 0; i < 32; i++) {
            hd = fmaf(enc[i], colD[i], hd);
            hf = fmaf(enc[i], colF[i], hf);
        }
        hd = fmaxf(hd, 0.0f);
        hf = fmaxf(hf, 0.0f);
        dacc = fmaf(hd, sDw2[j], dacc);
        c0 = fmaf(hf, sFw2[j * 3 + 0], c0);
        c1 = fmaf(hf, sFw2[j * 3 + 1], c1);
        c2 = fmaf(hf, sFw2[j * 3 + 2], c2);
    }

    float density = (dacc > 20.0f) ? dacc : log1pf(expf(dacc));
    out[gid * 3 + 0] = 1.0f / (1.0f + expf(-c0));
    out[gid * 3 + 1] = 1.0f / (1.0f + expf(-c1));
    out[gid * 3 + 2] = 1.0f / (1.0f + expf(-c2));
    out[(size_t)3 * N + gid] = density;
}

extern "C" void kernel_launch(void* const* d_in, const int* in_sizes, int n_in,
                              void* d_out, int out_size, void* d_ws, size_t ws_size,
                              hipStream_t stream) {
    const float* points = (const float*)d_in[0];
    const float* table  = (const float*)d_in[1];
    const float* dw1    = (const float*)d_in[2];
    const float* dw2    = (const float*)d_in[3];
    const float* fw1    = (const float*)d_in[4];
    const float* fw2    = (const float*)d_in[5];
    int N = in_sizes[0] / 3;

    LevelConsts C;
    for (int l = 0; l < NLV; l++) {
        double s = 16.0 * pow(1.447269237440378, (double)l) - 1.0;
        C.scale[l] = (float)s;
        int res = (int)ceil(s) + 1;
        C.res[l] = res;
        C.dense[l] = ((long long)res * res * res <= (long long)TBL_SIZE) ? 1 : 0;
    }

    auto align256 = [](size_t x) { return (x + 255) & ~(size_t)255; };
    const size_t tbl_bytes  = align256((size_t)NLV * TBL_SIZE * 4);   // 32 MB
    const size_t enc_bytes  = align256((size_t)N * NLV * 4);          // 64 MB
    const size_t spts_bytes = align256((size_t)N * 4 * 4);            // 16 MB
    const size_t hist_bytes = align256((size_t)KB15 * 4);             // 128 KB

    int ntiles = (N + 255) / 256;
    int chunks = (N + 256 * ENC_P - 1) / (256 * ENC_P);
    int npairs = NLV * TBL_SIZE;

    // hist aliases the head of enc_ws (dead before encode writes enc).
    if (ws_size >= tbl_bytes + enc_bytes + spts_bytes && enc_bytes >= hist_bytes) {
        // ---- tier1: global 32^3 Morton sort via global atomics ----
        char* wp = (char*)d_ws;
        unsigned int* tbl_bf16 = (unsigned int*)wp;            wp += tbl_bytes;
        unsigned int* enc_ws   = (unsigned int*)wp;            wp += enc_bytes;
        f32x4*        spts4    = (f32x4*)wp;                   wp += spts_bytes;
        unsigned int* hist     = enc_ws;                       // alias

        hipMemsetAsync(hist, 0, (size_t)KB15 * 4, stream);
        cvt_and_hist_at<<<2048, 256, 0, stream>>>(table, tbl_bf16, npairs,
                                                  points, hist, N, 1024);
        scan_tot<<<1, SCAN_THREADS, 0, stream>>>(hist);
        scatter_at<<<1024, 256, 0, stream>>>(points, hist, spts4, N);

        encode_lvl<4><<<dim3(chunks, NLV), 256, 0, stream>>>((const float*)spts4,
                                                             tbl_bf16, enc_ws, N, C);
        mlp_kernel<<<1792, 256, 0, stream>>>(enc_ws, dw1, dw2, fw1, fw2,
                                             (const unsigned int*)spts4,
                                             (float*)d_out, N, ntiles);
    } else if (ws_size >= tbl_bytes + enc_bytes + spts_bytes) {
        // ---- tier2: block-local sort (proven R5 path) ----
        char* wp = (char*)d_ws;
        unsigned int* tbl_bf16 = (unsigned int*)wp;            wp += tbl_bytes;
        unsigned int* enc_ws   = (unsigned int*)wp;            wp += enc_bytes;
        f32x4*        spts4    = (f32x4*)wp;                   wp += spts_bytes;

        int sortBlocks = (N + SORT_PPB - 1) / SORT_PPB;
        cvt_and_sort<<<sortBlocks + 1024, SORT_THREADS, 0, stream>>>(
            table, tbl_bf16, npairs, points, spts4, N, sortBlocks);

        encode_lvl<4><<<dim3(chunks, NLV), 256, 0, stream>>>((const float*)spts4,
                                                             tbl_bf16, enc_ws, N, C);
        mlp_kernel<<<1792, 256, 0, stream>>>(enc_ws, dw1, dw2, fw1, fw2,
                                             (const unsigned int*)spts4,
                                             (float*)d_out, N, ntiles);
    } else if (ws_size >= tbl_bytes + enc_bytes) {
        unsigned int* tbl_bf16 = (unsigned int*)d_ws;
        unsigned int* enc_ws   = (unsigned int*)((char*)d_ws + tbl_bytes);

        cvt_table<<<1024, 256, 0, stream>>>(table, tbl_bf16, npairs);
        encode_lvl<3><<<dim3(chunks, NLV), 256, 0, stream>>>(points, tbl_bf16, enc_ws, N, C);
        mlp_kernel<<<1792, 256, 0, stream>>>(enc_ws, dw1, dw2, fw1, fw2, nullptr,
                                             (float*)d_out, N, ntiles);
    } else {
        int blocks = (N + 255) / 256;
        nerf_fused<<<blocks, 256, 0, stream>>>(points, table, dw1, dw2, fw1, fw2,
                                               (float*)d_out, N, C);
    }
}

// Round 10
// 508.047 us; speedup vs baseline: 1.1087x; 1.1087x over previous
//
#include <hip/hip_runtime.h>
#include <hip/hip_bf16.h>
#include <cmath>

#define NLV 16
#define TBL_SIZE (1u << 19)

// tier2 block-local sort (fallback)
#define SORT_PPB 8192
#define SORT_THREADS 512
#define SORT_NKEYS 4096

// tier1 global 3-pass sort
#define KB15 32768         // 32^3 Morton buckets
#define PPB2 16384         // points per hist window (64 windows @ N=1M)
#define GS_THREADS 1024
#define CSCAN_THREADS 64
#define SCAN_THREADS 1024

struct LevelConsts {
    float scale[NLV];
    int   res[NLV];
    int   dense[NLV];
};

// ---------- bf16 helpers ----------
__device__ __forceinline__ unsigned int f32_to_bf16_rne(float f) {
    unsigned int u = __float_as_uint(f);
    return (u + 0x7FFFu + ((u >> 16) & 1u)) >> 16;
}
__device__ __forceinline__ unsigned int pack_bf16(float a, float b) {
    return f32_to_bf16_rne(a) | (f32_to_bf16_rne(b) << 16);
}
__device__ __forceinline__ short f32_to_bf16_s(float f) {
    return (short)f32_to_bf16_rne(f);
}
__device__ __forceinline__ float bf16lo_to_f32(unsigned int g) {
    return __uint_as_float(g << 16);
}
__device__ __forceinline__ float bf16hi_to_f32(unsigned int g) {
    return __uint_as_float(g & 0xFFFF0000u);
}

typedef __attribute__((ext_vector_type(8))) short bf16x8;
typedef __attribute__((ext_vector_type(4))) float f32x4;
typedef __attribute__((ext_vector_type(2))) unsigned int u32x2;
typedef __attribute__((ext_vector_type(4))) unsigned int u32x4;

// ---------- Morton keys ----------
__device__ __forceinline__ unsigned spread3(unsigned x) {
    x &= 0x3FFu;
    x = (x | (x << 16)) & 0x030000FFu;
    x = (x | (x << 8))  & 0x0300F00Fu;
    x = (x | (x << 4))  & 0x030C30C3u;
    x = (x | (x << 2))  & 0x09249249u;
    return x;
}
__device__ __forceinline__ unsigned key12(float px, float py, float pz) {
    float x = fminf(fmaxf((px + 1.0f) * 0.5f, 0.0f), 1.0f);
    float y = fminf(fmaxf((py + 1.0f) * 0.5f, 0.0f), 1.0f);
    float z = fminf(fmaxf((pz + 1.0f) * 0.5f, 0.0f), 1.0f);
    int ix = min((int)(x * 16.0f), 15);
    int iy = min((int)(y * 16.0f), 15);
    int iz = min((int)(z * 16.0f), 15);
    return spread3((unsigned)ix) | (spread3((unsigned)iy) << 1) | (spread3((unsigned)iz) << 2);
}
__device__ __forceinline__ unsigned key15(float px, float py, float pz) {
    float x = fminf(fmaxf((px + 1.0f) * 0.5f, 0.0f), 1.0f);
    float y = fminf(fmaxf((py + 1.0f) * 0.5f, 0.0f), 1.0f);
    float z = fminf(fmaxf((pz + 1.0f) * 0.5f, 0.0f), 1.0f);
    int ix = min((int)(x * 32.0f), 31);
    int iy = min((int)(y * 32.0f), 31);
    int iz = min((int)(z * 32.0f), 31);
    return spread3((unsigned)ix) | (spread3((unsigned)iy) << 1) | (spread3((unsigned)iz) << 2);
}

// ---------- tier1 pass A: per-window LDS hist (packed ushort halves) || cvt ----
__global__ __launch_bounds__(GS_THREADS) void cvt_and_hist(
    const float* __restrict__ tablef32, unsigned int* __restrict__ tbl_out, int npairs,
    const float* __restrict__ pts, unsigned int* __restrict__ colpre32, // [nblk][KB15/2]
    int N, int histBlocks)
{
    __shared__ unsigned packed[KB15 / 2];   // 64 KB: key pair (2k,2k+1) in lo/hi half
    if ((int)blockIdx.x < histBlocks) {
        const int blk = blockIdx.x, base = blk * PPB2, cnt = min(PPB2, N - base);
        const int tid = threadIdx.x;
        for (int i = tid; i < KB15 / 2; i += GS_THREADS) packed[i] = 0u;
        __syncthreads();
#pragma unroll
        for (int q = 0; q < PPB2 / GS_THREADS; q++) {
            int idx = q * GS_THREADS + tid;
            if (idx < cnt) {
                int p = base + idx;
                unsigned k = key15(pts[3 * p + 0], pts[3 * p + 1], pts[3 * p + 2]);
                atomicAdd(&packed[k >> 1], (k & 1u) ? 0x10000u : 1u);
            }
        }
        __syncthreads();
        for (int i = tid; i < KB15 / 2; i += GS_THREADS)
            colpre32[(size_t)blk * (KB15 / 2) + i] = packed[i];
    } else {
        int b = blockIdx.x - histBlocks;
        int n2 = npairs >> 1;
        int i = b * GS_THREADS + threadIdx.x;
        int stride = ((int)gridDim.x - histBlocks) * GS_THREADS;
        const f32x4* in4 = (const f32x4*)tablef32;
        u32x2* out2 = (u32x2*)tbl_out;
        for (; i < n2; i += stride) {
            f32x4 v = __builtin_nontemporal_load(&in4[i]);
            u32x2 o;
            o.x = pack_bf16(v.x, v.y);
            o.y = pack_bf16(v.z, v.w);
            __builtin_nontemporal_store(o, &out2[i]);
        }
    }
}

// ---------- tier1 pass B1: column scan (full-chip: 256 blocks x 64 thr) ----------
__global__ __launch_bounds__(CSCAN_THREADS) void colscan(
    unsigned int* __restrict__ colpre32, unsigned int* __restrict__ tot, int nblk)
{
    int k2 = blockIdx.x * CSCAN_THREADS + threadIdx.x;   // pair index < KB15/2
    unsigned run0 = 0, run1 = 0;
    int b = 0;
    for (; b + 4 <= nblk; b += 4) {
        size_t o0 = (size_t)b * (KB15 / 2) + k2;
        unsigned v0 = colpre32[o0];
        unsigned v1 = colpre32[o0 + (size_t)(KB15 / 2)];
        unsigned v2 = colpre32[o0 + (size_t)2 * (KB15 / 2)];
        unsigned v3 = colpre32[o0 + (size_t)3 * (KB15 / 2)];
        colpre32[o0] = run0 | (run1 << 16);
        run0 += v0 & 0xFFFFu; run1 += v0 >> 16;
        colpre32[o0 + (size_t)(KB15 / 2)] = run0 | (run1 << 16);
        run0 += v1 & 0xFFFFu; run1 += v1 >> 16;
        colpre32[o0 + (size_t)2 * (KB15 / 2)] = run0 | (run1 << 16);
        run0 += v2 & 0xFFFFu; run1 += v2 >> 16;
        colpre32[o0 + (size_t)3 * (KB15 / 2)] = run0 | (run1 << 16);
        run0 += v3 & 0xFFFFu; run1 += v3 >> 16;
    }
    for (; b < nblk; b++) {
        size_t off = (size_t)b * (KB15 / 2) + k2;
        unsigned v = colpre32[off];
        colpre32[off] = run0 | (run1 << 16);
        run0 += v & 0xFFFFu;
        run1 += v >> 16;
    }
    tot[2 * k2 + 0] = run0;
    tot[2 * k2 + 1] = run1;
}

// ---------- tier1 pass B2: exclusive scan of tot[KB15] (one block) ----------
__global__ __launch_bounds__(SCAN_THREADS) void scan_tot(unsigned int* __restrict__ tot) {
    __shared__ unsigned wsum[SCAN_THREADS / 64];
    const int t = threadIdx.x, lane = t & 63, wid = t >> 6;
    unsigned loc[KB15 / SCAN_THREADS];
    unsigned s = 0;
#pragma unroll
    for (int j = 0; j < KB15 / SCAN_THREADS; j++) { loc[j] = tot[t * (KB15 / SCAN_THREADS) + j]; s += loc[j]; }
    unsigned x = s;
#pragma unroll
    for (int d = 1; d < 64; d <<= 1) {
        unsigned y = __shfl_up(x, d, 64);
        if (lane >= d) x += y;
    }
    unsigned wex = x - s;
    if (lane == 63) wsum[wid] = x;
    __syncthreads();
    if (t == 0) {
        unsigned r = 0;
        for (int i = 0; i < SCAN_THREADS / 64; i++) { unsigned tt = wsum[i]; wsum[i] = r; r += tt; }
    }
    __syncthreads();
    unsigned run = wex + wsum[wid];
#pragma unroll
    for (int j = 0; j < KB15 / SCAN_THREADS; j++) { tot[t * (KB15 / SCAN_THREADS) + j] = run; run += loc[j]; }
}

// ---------- tier1 pass C: per-window cursor scatter (full chip) ----------
// colpre (post-colscan) holds exclusive within-column prefixes; consume its
// packed u16 halves as per-(window,bucket) cursors via global atomics. 4 MB of
// cursors = 32K lines -> ~30 atomics/line (no L2 line serialization, unlike the
// 128KB-hist variant). Intra-bucket order nondeterministic; final output is
// scattered back by original index, so results stay order-independent.
__global__ __launch_bounds__(256) void scatter_cursor(
    const float* __restrict__ pts, unsigned int* __restrict__ colpre32,
    const unsigned int* __restrict__ tot, f32x4* __restrict__ spts4, int N)
{
    int i = blockIdx.x * 256 + threadIdx.x;
    int stride = gridDim.x * 256;
    for (; i < N; i += stride) {
        float px = pts[3 * i + 0];
        float py = pts[3 * i + 1];
        float pz = pts[3 * i + 2];
        unsigned k = key15(px, py, pz);
        unsigned w = (unsigned)i / PPB2;
        unsigned old = atomicAdd(&colpre32[(size_t)w * (KB15 / 2) + (k >> 1)],
                                 (k & 1u) ? 0x10000u : 1u);
        unsigned cr = (k & 1u) ? (old >> 16) : (old & 0xFFFFu);  // colbase + rank
        unsigned pos = tot[k] + cr;
        f32x4 o;
        o.x = px; o.y = py; o.z = pz; o.w = __uint_as_float((unsigned)i);
        spts4[pos] = o;
    }
}

// ---------- tier2: fused cvt || block-local sort (proven R5 path) ------
__global__ __launch_bounds__(SORT_THREADS) void cvt_and_sort(
    const float* __restrict__ tablef32, unsigned int* __restrict__ tbl_out, int npairs,
    const float* __restrict__ pts, f32x4* __restrict__ spts4, int N, int sortBlocks)
{
    __shared__ unsigned hist[SORT_NKEYS];
    __shared__ unsigned wsum[SORT_THREADS / 64];

    if ((int)blockIdx.x < sortBlocks) {
        const int sb   = blockIdx.x;
        const int base = sb * SORT_PPB;
        const int cnt  = min(SORT_PPB, N - base);
        const int tid  = threadIdx.x;
        const int lane = tid & 63, wid = tid >> 6;

        for (int i = tid; i < SORT_NKEYS; i += SORT_THREADS) hist[i] = 0u;
        __syncthreads();

        unsigned short keys[16];
#pragma unroll
        for (int q = 0; q < 16; q++) {
            int idx = q * SORT_THREADS + tid;
            unsigned k = 0xFFFFu;
            if (idx < cnt) {
                int p = base + idx;
                k = key12(pts[3 * p + 0], pts[3 * p + 1], pts[3 * p + 2]);
                atomicAdd(&hist[k], 1u);
            }
            keys[q] = (unsigned short)k;
        }
        __syncthreads();

        unsigned loc[8], s = 0;
#pragma unroll
        for (int j = 0; j < 8; j++) { loc[j] = hist[tid * 8 + j]; s += loc[j]; }
        unsigned x = s;
#pragma unroll
        for (int d = 1; d < 64; d <<= 1) {
            unsigned y = __shfl_up(x, d, 64);
            if (lane >= d) x += y;
        }
        unsigned wex = x - s;
        if (lane == 63) wsum[wid] = x;
        __syncthreads();
        if (tid == 0) {
            unsigned r = 0;
            for (int i = 0; i < SORT_THREADS / 64; i++) { unsigned t2 = wsum[i]; wsum[i] = r; r += t2; }
        }
        __syncthreads();
        unsigned run = wex + wsum[wid];
#pragma unroll
        for (int j = 0; j < 8; j++) { hist[tid * 8 + j] = run; run += loc[j]; }
        __syncthreads();

#pragma unroll
        for (int q = 0; q < 16; q++) {
            int idx = q * SORT_THREADS + tid;
            if (idx < cnt) {
                int p = base + idx;
                float px = pts[3 * p + 0];
                float py = pts[3 * p + 1];
                float pz = pts[3 * p + 2];
                unsigned pos = atomicAdd(&hist[keys[q]], 1u);
                f32x4 o;
                o.x = px; o.y = py; o.z = pz; o.w = __uint_as_float((unsigned)p);
                spts4[base + pos] = o;
            }
        }
    } else {
        int b = blockIdx.x - sortBlocks;
        int n2 = npairs >> 1;
        int i = b * SORT_THREADS + threadIdx.x;
        int stride = ((int)gridDim.x - sortBlocks) * SORT_THREADS;
        const f32x4* in4 = (const f32x4*)tablef32;
        u32x2* out2 = (u32x2*)tbl_out;
        for (; i < n2; i += stride) {
            f32x4 v = __builtin_nontemporal_load(&in4[i]);
            u32x2 o;
            o.x = pack_bf16(v.x, v.y);
            o.y = pack_bf16(v.z, v.w);
            __builtin_nontemporal_store(o, &out2[i]);
        }
    }
}

// standalone cvt for tier3
__global__ __launch_bounds__(256) void cvt_table(const float* __restrict__ in,
                                                 unsigned int* __restrict__ out, int npairs) {
    int n2 = npairs >> 1;
    int i = blockIdx.x * 256 + threadIdx.x;
    int stride = gridDim.x * 256;
    const f32x4* in4 = (const f32x4*)in;
    u32x2* out2 = (u32x2*)out;
    for (; i < n2; i += stride) {
        f32x4 v = __builtin_nontemporal_load(&in4[i]);
        u32x2 o;
        o.x = pack_bf16(v.x, v.y);
        o.y = pack_bf16(v.z, v.w);
        __builtin_nontemporal_store(o, &out2[i]);
    }
}

// ---------- kernel B: level-major hash-grid encode ----------
// 2D grid, blockIdx.y = level. DO NOT flatten: x-major dispatch order keeps
// only 1-2 levels' tables (2-4MB) hot in L2 at any instant — this temporal
// level-locality is the load-bearing optimization (R4 flattening: 265->455us).
#define ENC_P 4
template<int PSTRIDE>
__global__ __launch_bounds__(256) void encode_lvl(
    const float* __restrict__ points,
    const unsigned int* __restrict__ tbl,
    unsigned int* __restrict__ enc,
    int N, LevelConsts C)
{
    const int level = blockIdx.y;
    const float sc    = C.scale[level];
    const int   res   = C.res[level];
    const int   dense = C.dense[level];
    const unsigned int* __restrict__ t = tbl + (size_t)level * TBL_SIZE;
    unsigned int* __restrict__ eo = enc + (size_t)level * N;

    const int base = blockIdx.x * (256 * ENC_P) + threadIdx.x;

    int   pt[ENC_P];
    int   valid[ENC_P];
    float wx[ENC_P], wy[ENC_P], wz[ENC_P];
    unsigned int i0a[ENC_P][4], i1a[ENC_P][4];

#pragma unroll
    for (int q = 0; q < ENC_P; q++) {
        pt[q] = base + q * 256;
        valid[q] = pt[q] < N;
        int p = valid[q] ? pt[q] : 0;
        float px, py, pz;
        if (PSTRIDE == 4) {
            f32x4 v = *(const f32x4*)&points[(size_t)p * 4];
            px = v.x; py = v.y; pz = v.z;
        } else {
            px = points[p * 3 + 0];
            py = points[p * 3 + 1];
            pz = points[p * 3 + 2];
        }
        float x = fminf(fmaxf((px + 1.0f) * 0.5f, 0.0f), 1.0f);
        float y = fminf(fmaxf((py + 1.0f) * 0.5f, 0.0f), 1.0f);
        float z = fminf(fmaxf((pz + 1.0f) * 0.5f, 0.0f), 1.0f);

        float fx = x * sc + 0.5f;
        float fy = y * sc + 0.5f;
        float fz = z * sc + 0.5f;
        float f0x = floorf(fx), f0y = floorf(fy), f0z = floorf(fz);
        wx[q] = fx - f0x; wy[q] = fy - f0y; wz[q] = fz - f0z;
        int ix0 = min(max((int)f0x, 0), res - 1);
        int iy0 = min(max((int)f0y, 0), res - 1);
        int iz0 = min(max((int)f0z, 0), res - 1);
        int ix1 = min(ix0 + 1, res - 1);
        int iy1 = min(iy0 + 1, res - 1);
        int iz1 = min(iz0 + 1, res - 1);

#pragma unroll
        for (int m = 0; m < 4; m++) {
            unsigned int uy = (unsigned int)((m & 1) ? iy1 : iy0);
            unsigned int uz = (unsigned int)((m & 2) ? iz1 : iz0);
            unsigned int i0, i1;
            if (dense) {
                unsigned int b = (unsigned int)res * uy + (unsigned int)(res * res) * uz;
                i0 = (unsigned int)ix0 + b;
                i1 = (unsigned int)ix1 + b;
            } else {
                unsigned int H = uy * 2654435761u ^ uz * 805459861u;
                i0 = ((unsigned int)ix0 ^ H) & (TBL_SIZE - 1u);
                i1 = ((unsigned int)ix1 ^ H) & (TBL_SIZE - 1u);
            }
            i0a[q][m] = i0;
            i1a[q][m] = i1;
        }
    }

    u32x2 pr[ENC_P][4];
#pragma unroll
    for (int q = 0; q < ENC_P; q++)
#pragma unroll
        for (int m = 0; m < 4; m++)
            pr[q][m] = *(const u32x2*)(t + (i0a[q][m] & ~1u));

    unsigned int ex[ENC_P][4];
#pragma unroll
    for (int q = 0; q < ENC_P; q++)
#pragma unroll
        for (int m = 0; m < 4; m++) {
            unsigned int i0 = i0a[q][m], i1 = i1a[q][m];
            unsigned int e = 0u;
            if (i1 != (i0 ^ 1u)) e = t[i1];
            ex[q][m] = e;
        }

#pragma unroll
    for (int q = 0; q < ENC_P; q++) {
        float e0 = 0.0f, e1 = 0.0f;
        float wxq = wx[q];
#pragma unroll
        for (int m = 0; m < 4; m++) {
            unsigned int i0 = i0a[q][m], i1 = i1a[q][m];
            u32x2 P = pr[q][m];
            unsigned int v0   = (i0 & 1u) ? P.y : P.x;
            unsigned int vpar = (i0 & 1u) ? P.x : P.y;
            unsigned int v1   = (i1 == (i0 ^ 1u)) ? vpar : ex[q][m];
            float wyz = (((m & 1) ? wy[q] : 1.0f - wy[q])) *
                        (((m & 2) ? wz[q] : 1.0f - wz[q]));
            float w0 = wyz * (1.0f - wxq);
            float w1 = wyz * wxq;
            e0 = fmaf(w0, bf16lo_to_f32(v0), e0);
            e0 = fmaf(w1, bf16lo_to_f32(v1), e0);
            e1 = fmaf(w0, bf16hi_to_f32(v0), e1);
            e1 = fmaf(w1, bf16hi_to_f32(v1), e1);
        }
        if (valid[q]) __builtin_nontemporal_store(pack_bf16(e0, e1), &eo[pt[q]]);
    }
}

// ---------- kernel C: persistent fused dual-MLP via MFMA ----------
// Weight setup: dw1/fw1 staged COALESCED into LDS (overlaid on hsh, barrier
// separated) instead of 64 strided scalar loads per thread; grid sized so all
// blocks are resident and each runs ~4 tiles (setup amortization).
__global__ __launch_bounds__(256, 4) void mlp_kernel(
    const unsigned int* __restrict__ enc,
    const float* __restrict__ dw1, const float* __restrict__ dw2,
    const float* __restrict__ fw1, const float* __restrict__ fw2,
    const unsigned int* __restrict__ perm,   // spts4.w (stride 4), or null
    float* __restrict__ out, int N, int ntiles)
{
    __shared__ unsigned int hsh[4][16][68];
    __shared__ float sOut[4][256];

    const int tid  = threadIdx.x;
    const int wave = tid >> 6;
    const int lane = tid & 63;
    const int l15 = lane & 15;
    const int quad = lane >> 4;

    // --- stage W1 coalesced through LDS (overlay on hsh; dead until main loop)
    float* sW = (float*)hsh;   // 2048 floats needed; hsh = 17.4 KB >= 8 KB
    bf16x8 B1[8];
    for (int i = tid; i < 2048; i += 256) sW[i] = dw1[i];
    __syncthreads();
#pragma unroll
    for (int nt = 0; nt < 4; nt++) {
        int col = nt * 16 + l15;
#pragma unroll
        for (int j = 0; j < 8; j++)
            B1[nt][j] = f32_to_bf16_s(sW[(quad * 8 + j) * 64 + col]);
    }
    __syncthreads();
    for (int i = tid; i < 2048; i += 256) sW[i] = fw1[i];
    __syncthreads();
#pragma unroll
    for (int nt = 4; nt < 8; nt++) {
        int col = nt * 16 + l15 - 64;
#pragma unroll
        for (int j = 0; j < 8; j++)
            B1[nt][j] = f32_to_bf16_s(sW[(quad * 8 + j) * 64 + col]);
    }
    __syncthreads();

    bf16x8 B2[4];
#pragma unroll
    for (int s = 0; s < 4; s++) {
#pragma unroll
        for (int j = 0; j < 8; j++) {
            int k_lds = s * 32 + quad * 8 + j;
            int hu = ((k_lds & 7) << 4) | (k_lds >> 3);
            float v = 0.0f;
            if (l15 == 0)      v = (hu < 64)  ? dw2[hu] : 0.0f;
            else if (l15 < 4)  v = (hu >= 64) ? fw2[(hu - 64) * 3 + (l15 - 1)] : 0.0f;
            B2[s][j] = f32_to_bf16_s(v);
        }
    }

    for (int tile = blockIdx.x; tile < ntiles; tile += gridDim.x) {
        const int wbase = tile * 256 + wave * 64;

        unsigned int au[4][4];
#pragma unroll
        for (int sub = 0; sub < 4; sub++) {
            int ptc = min(wbase + sub * 16 + l15, N - 1);
#pragma unroll
            for (int j = 0; j < 4; j++)
                au[sub][j] = enc[(size_t)(quad * 4 + j) * N + ptc];
        }

#pragma unroll
        for (int sub = 0; sub < 4; sub++) {
            union { unsigned int u[4]; bf16x8 v; } acvt;
#pragma unroll
            for (int j = 0; j < 4; j++) acvt.u[j] = au[sub][j];

            f32x4 acc1[8];
#pragma unroll
            for (int nt = 0; nt < 8; nt++) {
                acc1[nt] = (f32x4){0.0f, 0.0f, 0.0f, 0.0f};
                acc1[nt] = __builtin_amdgcn_mfma_f32_16x16x32_bf16(acvt.v, B1[nt], acc1[nt], 0, 0, 0);
            }

#pragma unroll
            for (int r = 0; r < 4; r++) {
                u32x4 pk;
#pragma unroll
                for (int d = 0; d < 4; d++) {
                    float h0 = fmaxf(acc1[2 * d + 0][r], 0.0f);
                    float h1 = fmaxf(acc1[2 * d + 1][r], 0.0f);
                    pk[d] = pack_bf16(h0, h1);
                }
                *(u32x4*)&hsh[wave][quad * 4 + r][l15 * 4] = pk;
            }

            f32x4 p0 = (f32x4){0,0,0,0}, p1 = (f32x4){0,0,0,0};
            f32x4 p2 = (f32x4){0,0,0,0}, p3 = (f32x4){0,0,0,0};
            {
                bf16x8 a0 = *(const bf16x8*)&hsh[wave][l15][0 * 16 + quad * 4];
                bf16x8 a1 = *(const bf16x8*)&hsh[wave][l15][1 * 16 + quad * 4];
                bf16x8 a2 = *(const bf16x8*)&hsh[wave][l15][2 * 16 + quad * 4];
                bf16x8 a3 = *(const bf16x8*)&hsh[wave][l15][3 * 16 + quad * 4];
                p0 = __builtin_amdgcn_mfma_f32_16x16x32_bf16(a0, B2[0], p0, 0, 0, 0);
                p1 = __builtin_amdgcn_mfma_f32_16x16x32_bf16(a1, B2[1], p1, 0, 0, 0);
                p2 = __builtin_amdgcn_mfma_f32_16x16x32_bf16(a2, B2[2], p2, 0, 0, 0);
                p3 = __builtin_amdgcn_mfma_f32_16x16x32_bf16(a3, B2[3], p3, 0, 0, 0);
            }
            f32x4 acc2;
#pragma unroll
            for (int r = 0; r < 4; r++) acc2[r] = (p0[r] + p1[r]) + (p2[r] + p3[r]);

            if (l15 < 4) {
#pragma unroll
                for (int r = 0; r < 4; r++)
                    sOut[wave][(sub * 16 + quad * 4 + r) * 4 + l15] = acc2[r];
            }
        }

        if (perm) {
            int p = wbase + lane;
            if (p < N) {
                unsigned int o = perm[(size_t)p * 4 + 3];
                f32x4 v = *(const f32x4*)&sOut[wave][lane * 4];
                float d = v[0];
                d = (d > 20.0f) ? d : log1pf(expf(d));
                out[(size_t)3 * N + o] = d;
                float r0 = 1.0f / (1.0f + expf(-v[1]));
                float g0 = 1.0f / (1.0f + expf(-v[2]));
                float b0 = 1.0f / (1.0f + expf(-v[3]));
                out[(size_t)o * 3 + 0] = r0;
                out[(size_t)o * 3 + 1] = g0;
                out[(size_t)o * 3 + 2] = b0;
            }
        } else {
            long long cmax = ((long long)N - wbase) * 3;
#pragma unroll
            for (int round = 0; round < 3; round++) {
                int f = round * 64 + lane;
                int lp = f / 3, c = f - lp * 3;
                float v = sOut[wave][lp * 4 + 1 + c];
                v = 1.0f / (1.0f + expf(-v));
                if (f < cmax) out[(size_t)wbase * 3 + f] = v;
            }
            {
                int p = wbase + lane;
                float v = sOut[wave][lane * 4];
                v = (v > 20.0f) ? v : log1pf(expf(v));
                if (p < N) out[(size_t)3 * N + p] = v;
            }
        }
    }
}

// ---------- fallback: round-1 fused kernel (tiny ws) ----------
__global__ __launch_bounds__(256) void nerf_fused(
    const float* __restrict__ points,
    const float* __restrict__ table,
    const float* __restrict__ dw1, const float* __restrict__ dw2,
    const float* __restrict__ fw1, const float* __restrict__ fw2,
    float* __restrict__ out, int N, LevelConsts C)
{
    __shared__ float sD[64 * 32];
    __shared__ float sF[64 * 32];
    __shared__ float sDw2[64];
    __shared__ float sFw2[64 * 3];

    for (int idx = threadIdx.x; idx < 2048; idx += 256) {
        int i = idx >> 6;
        int j = idx & 63;
        sD[j * 32 + i] = dw1[idx];
        sF[j * 32 + i] = fw1[idx];
    }
    if (threadIdx.x < 64)  sDw2[threadIdx.x] = dw2[threadIdx.x];
    if (threadIdx.x < 192) sFw2[threadIdx.x] = fw2[threadIdx.x];
    __syncthreads();

    int gid = blockIdx.x * 256 + threadIdx.x;
    if (gid >= N) return;

    float px = points[gid * 3 + 0];
    float py = points[gid * 3 + 1];
    float pz = points[gid * 3 + 2];
    float x = fminf(fmaxf((px + 1.0f) * 0.5f, 0.0f), 1.0f);
    float y = fminf(fmaxf((py + 1.0f) * 0.5f, 0.0f), 1.0f);
    float z = fminf(fmaxf((pz + 1.0f) * 0.5f, 0.0f), 1.0f);

    float enc[32];

#pragma unroll
    for (int l = 0; l < NLV; l++) {
        const float sc = C.scale[l];
        const int   res = C.res[l];
        const int   dense = C.dense[l];
        const float* __restrict__ tbl = table + (size_t)l * TBL_SIZE * 2;

        float fx = x * sc + 0.5f;
        float fy = y * sc + 0.5f;
        float fz = z * sc + 0.5f;
        float f0x = floorf(fx), f0y = floorf(fy), f0z = floorf(fz);
        float wx = fx - f0x, wy = fy - f0y, wz = fz - f0z;
        int ix0 = min(max((int)f0x, 0), res - 1);
        int iy0 = min(max((int)f0y, 0), res - 1);
        int iz0 = min(max((int)f0z, 0), res - 1);
        int ix1 = min(ix0 + 1, res - 1);
        int iy1 = min(iy0 + 1, res - 1);
        int iz1 = min(iz0 + 1, res - 1);

        float e0 = 0.0f, e1 = 0.0f;
#pragma unroll
        for (int c = 0; c < 8; c++) {
            int cx = (c & 4) ? ix1 : ix0;
            int cy = (c & 2) ? iy1 : iy0;
            int cz = (c & 1) ? iz1 : iz0;
            float wgt = (((c & 4) ? wx : 1.0f - wx) *
                         ((c & 2) ? wy : 1.0f - wy)) *
                         ((c & 1) ? wz : 1.0f - wz);
            unsigned int idx;
            if (dense) {
                idx = (unsigned int)(cx + res * cy + res * res * cz);
            } else {
                idx = ((unsigned int)cx * 1u
                     ^ (unsigned int)cy * 2654435761u
                     ^ (unsigned int)cz * 805459861u) & (TBL_SIZE - 1u);
            }
            const float2 g = *(const float2*)(tbl + (size_t)idx * 2);
            e0 = fmaf(wgt, g.x, e0);
            e1 = fmaf(wgt, g.y, e1);
        }
        enc[2 * l + 0] = e0;
        enc[2 * l + 1] = e1;
    }

    float dacc = 0.0f, c0 = 0.0f, c1 = 0.0f, c2 = 0.0f;
    for (int j = 0; j < 64; j++) {
        float hd = 0.0f, hf = 0.0f;
        const float* __restrict__ colD = &sD[j * 32];
        const float* __restrict__ colF = &sF[j * 32];
#pragma unroll
        for (int i = 0; i < 32; i++) {
            hd = fmaf(enc[i], colD[i], hd);
            hf = fmaf(enc[i], colF[i], hf);
        }
        hd = fmaxf(hd, 0.0f);
        hf = fmaxf(hf, 0.0f);
        dacc = fmaf(hd, sDw2[j], dacc);
        c0 = fmaf(hf, sFw2[j * 3 + 0], c0);
        c1 = fmaf(hf, sFw2[j * 3 + 1], c1);
        c2 = fmaf(hf, sFw2[j * 3 + 2], c2);
    }

    float density = (dacc > 20.0f) ? dacc : log1pf(expf(dacc));
    out[gid * 3 + 0] = 1.0f / (1.0f + expf(-c0));
    out[gid * 3 + 1] = 1.0f / (1.0f + expf(-c1));
    out[gid * 3 + 2] = 1.0f / (1.0f + expf(-c2));
    out[(size_t)3 * N + gid] = density;
}

extern "C" void kernel_launch(void* const* d_in, const int* in_sizes, int n_in,
                              void* d_out, int out_size, void* d_ws, size_t ws_size,
                              hipStream_t stream) {
    const float* points = (const float*)d_in[0];
    const float* table  = (const float*)d_in[1];
    const float* dw1    = (const float*)d_in[2];
    const float* dw2    = (const float*)d_in[3];
    const float* fw1    = (const float*)d_in[4];
    const float* fw2    = (const float*)d_in[5];
    int N = in_sizes[0] / 3;

    LevelConsts C;
    for (int l = 0; l < NLV; l++) {
        double s = 16.0 * pow(1.447269237440378, (double)l) - 1.0;
        C.scale[l] = (float)s;
        int res = (int)ceil(s) + 1;
        C.res[l] = res;
        C.dense[l] = ((long long)res * res * res <= (long long)TBL_SIZE) ? 1 : 0;
    }

    auto align256 = [](size_t x) { return (x + 255) & ~(size_t)255; };
    const size_t tbl_bytes  = align256((size_t)NLV * TBL_SIZE * 4);   // 32 MB
    const size_t enc_bytes  = align256((size_t)N * NLV * 4);          // 64 MB
    const size_t spts_bytes = align256((size_t)N * 4 * 4);            // 16 MB

    int nblk = (N + PPB2 - 1) / PPB2;
    const size_t colpre_bytes = align256((size_t)nblk * (KB15 / 2) * 4); // 4 MB @ N=1M
    const size_t tot_bytes    = align256((size_t)KB15 * 4);              // 128 KB

    int ntiles = (N + 255) / 256;
    int chunks = (N + 256 * ENC_P - 1) / (256 * ENC_P);
    int npairs = NLV * TBL_SIZE;

    // colpre+tot alias onto enc_ws head (dead before encode writes enc).
    if (ws_size >= tbl_bytes + enc_bytes + spts_bytes &&
        enc_bytes >= colpre_bytes + tot_bytes) {
        // ---- tier1: global 32^3 Morton sort, 3-pass, full-chip passes ----
        char* wp = (char*)d_ws;
        unsigned int* tbl_bf16 = (unsigned int*)wp;            wp += tbl_bytes;
        unsigned int* enc_ws   = (unsigned int*)wp;            wp += enc_bytes;
        f32x4*        spts4    = (f32x4*)wp;                   wp += spts_bytes;
        unsigned int* colpre   = enc_ws;                                  // alias
        unsigned int* tot      = (unsigned int*)((char*)enc_ws + colpre_bytes); // alias

        cvt_and_hist<<<nblk + 512, GS_THREADS, 0, stream>>>(
            table, tbl_bf16, npairs, points, colpre, N, nblk);
        colscan<<<(KB15 / 2) / CSCAN_THREADS, CSCAN_THREADS, 0, stream>>>(colpre, tot, nblk);
        scan_tot<<<1, SCAN_THREADS, 0, stream>>>(tot);
        scatter_cursor<<<1024, 256, 0, stream>>>(points, colpre, tot, spts4, N);

        encode_lvl<4><<<dim3(chunks, NLV), 256, 0, stream>>>((const float*)spts4,
                                                             tbl_bf16, enc_ws, N, C);
        mlp_kernel<<<min(ntiles, 1024), 256, 0, stream>>>(enc_ws, dw1, dw2, fw1, fw2,
                                             (const unsigned int*)spts4,
                                             (float*)d_out, N, ntiles);
    } else if (ws_size >= tbl_bytes + enc_bytes + spts_bytes) {
        // ---- tier2: block-local sort (proven R5 path) ----
        char* wp = (char*)d_ws;
        unsigned int* tbl_bf16 = (unsigned int*)wp;            wp += tbl_bytes;
        unsigned int* enc_ws   = (unsigned int*)wp;            wp += enc_bytes;
        f32x4*        spts4    = (f32x4*)wp;                   wp += spts_bytes;

        int sortBlocks = (N + SORT_PPB - 1) / SORT_PPB;
        cvt_and_sort<<<sortBlocks + 1024, SORT_THREADS, 0, stream>>>(
            table, tbl_bf16, npairs, points, spts4, N, sortBlocks);

        encode_lvl<4><<<dim3(chunks, NLV), 256, 0, stream>>>((const float*)spts4,
                                                             tbl_bf16, enc_ws, N, C);
        mlp_kernel<<<min(ntiles, 1024), 256, 0, stream>>>(enc_ws, dw1, dw2, fw1, fw2,
                                             (const unsigned int*)spts4,
                                             (float*)d_out, N, ntiles);
    } else if (ws_size >= tbl_bytes + enc_bytes) {
        unsigned int* tbl_bf16 = (unsigned int*)d_ws;
        unsigned int* enc_ws   = (unsigned int*)((char*)d_ws + tbl_bytes);

        cvt_table<<<1024, 256, 0, stream>>>(table, tbl_bf16, npairs);
        encode_lvl<3><<<dim3(chunks, NLV), 256, 0, stream>>>(points, tbl_bf16, enc_ws, N, C);
        mlp_kernel<<<min(ntiles, 1024), 256, 0, stream>>>(enc_ws, dw1, dw2, fw1, fw2, nullptr,
                                             (float*)d_out, N, ntiles);
    } else {
        int blocks = (N + 255) / 256;
        nerf_fused<<<blocks, 256, 0, stream>>>(points, table, dw1, dw2, fw1, fw2,
                                               (float*)d_out, N, C);
    }
}